// Round 8
// baseline (716.844 us; speedup 1.0000x reference)
//
#include <hip/hip_runtime.h>
#include <hip/hip_bf16.h>
#include <cstdint>
#include <cstddef>

#define B_ 2
#define S_ 2048
#define E_ 4096
#define H_ 32
#define KVH_ 8
#define D_ 128
#define M_ (B_*S_)      // 4096 rows (B*S)
#define HD_ (H_*D_)     // 4096
#define KVD_ (KVH_*D_)  // 1024
#define NQKV_ 6144      // HD_ + 2*KVD_

typedef unsigned short u16;
typedef __attribute__((ext_vector_type(8))) short bf16x8;
typedef __attribute__((ext_vector_type(4))) float f32x4;
typedef __attribute__((ext_vector_type(16))) float f32x16;

__device__ __forceinline__ float bf2f(u16 u) {
  union { float f; uint32_t i; } v; v.i = ((uint32_t)u) << 16; return v.f;
}
__device__ __forceinline__ u16 f2bf(float f) {
  union { float f; uint32_t i; } v; v.f = f;
  uint32_t r = v.i + 0x7FFF + ((v.i >> 16) & 1);   // RNE
  return (u16)(r >> 16);
}

// async global->LDS, 16B per lane; LDS dest = wave-uniform base + lane*16
__device__ __forceinline__ void gload_lds16(const void* g, void* l) {
  __builtin_amdgcn_global_load_lds(
      (const __attribute__((address_space(1))) void*)g,
      (__attribute__((address_space(3))) void*)l, 16, 0, 0);
}

// ---------------- elementwise f32 -> bf16 ----------------
__global__ __launch_bounds__(256) void k_f2bf(const float* __restrict__ in,
                                              u16* __restrict__ out, int n) {
  int i = (blockIdx.x * 256 + threadIdx.x) * 4;
  if (i + 3 < n) {
    float4 v = *(const float4*)(in + i);
    *(ushort4*)(out + i) = make_ushort4(f2bf(v.x), f2bf(v.y), f2bf(v.z), f2bf(v.w));
  }
}

// ---------------- transpose-convert f32 [R][C] -> bf16 [C][R] ----------------
__global__ __launch_bounds__(256) void k_transpose_f2bf(const float* __restrict__ in,
                                                        u16* __restrict__ out, int R, int C) {
  __shared__ float tile[32][33];
  int c0 = blockIdx.x * 32, r0 = blockIdx.y * 32;
  int lx = threadIdx.x, ly = threadIdx.y;
#pragma unroll
  for (int yy = 0; yy < 32; yy += 8)
    tile[ly + yy][lx] = in[(size_t)(r0 + ly + yy) * C + c0 + lx];
  __syncthreads();
#pragma unroll
  for (int yy = 0; yy < 32; yy += 8)
    out[(size_t)(c0 + ly + yy) * R + r0 + lx] = f2bf(tile[lx][ly + yy]);
}

// ---------- transpose v cols of qkvlin -> vt [B][KVH][D][S] (bf16) ----------
__global__ __launch_bounds__(256) void k_transpose_v(const u16* __restrict__ vlin,
                                                     u16* __restrict__ vt, int stride) {
  __shared__ u16 tile[32][33];
  int bk = blockIdx.z;             // b*KVH + kvh
  int b = bk >> 3, kvh = bk & 7;
  int s0 = blockIdx.x * 32, d0 = blockIdx.y * 32;
  int lx = threadIdx.x, ly = threadIdx.y;
#pragma unroll
  for (int yy = 0; yy < 32; yy += 8)
    tile[ly + yy][lx] = vlin[(size_t)(b * S_ + s0 + ly + yy) * stride + kvh * D_ + d0 + lx];
  __syncthreads();
#pragma unroll
  for (int yy = 0; yy < 32; yy += 8)
    vt[((size_t)bk * D_ + d0 + ly + yy) * S_ + s0 + lx] = tile[lx][ly + yy];
}

// ---------------- RoPE sin/cos table [S][64] ----------------
__global__ __launch_bounds__(256) void k_table(float2* __restrict__ tab) {
  int i = blockIdx.x * 256 + threadIdx.x;
  if (i < S_ * 64) {
    int s = i >> 6, d = i & 63;
    float inv = powf(10000.0f, -(float)d / 64.0f);
    float f = (float)s * inv;
    tab[i] = make_float2(sinf(f), cosf(f));
  }
}

// -------- RoPE + head reorder: strided cols of [B,S,*] -> [B,heads,S,D] --------
__global__ __launch_bounds__(256) void k_rope(const u16* __restrict__ in, u16* __restrict__ out,
                                              const float2* __restrict__ tab,
                                              const int* __restrict__ pos,
                                              int heads, int in_stride, int total) {
  int i = blockIdx.x * 256 + threadIdx.x;
  if (i >= total) return;
  int d = i & 63;
  int s = (i >> 6) & (S_ - 1);
  int bh = i >> 17;                 // 64*S_ = 2^17
  int h = bh % heads, b = bh / heads;
  size_t ibase = ((size_t)(b * S_ + s)) * in_stride + h * D_;
  float2 scv = tab[pos[b * S_ + s] * 64 + d];
  float x1 = bf2f(in[ibase + d]), x2 = bf2f(in[ibase + d + 64]);
  size_t obase = ((size_t)bh * S_ + s) * D_;
  out[obase + d]      = f2bf(x1 * scv.y - x2 * scv.x);
  out[obase + d + 64] = f2bf(x2 * scv.y + x1 * scv.x);
}

// ---------------- bf16 GEMM v3: C[M,N] = A[M,K] * BT[N,K]^T ----------------
// 128x128 tile, BK=64, 4 waves (2x2), 32x32x16 MFMA.
// LDS: 8-row groups padded to 1088B (group stride == 16 banks mod 32) so the
// 32-row frag reads alias at most 2 lanes/bank (free) instead of 4-way.
// elem(r,b) = (r>>3)*544 + (r&7)*64 + b*8; staging writes one 8-row group per
// gload call (1024B lane-linear, pad lives between calls).
template<bool OUTF32>
__global__ __launch_bounds__(256) void k_gemm_bt(const u16* __restrict__ A,
                                                 const u16* __restrict__ BT,
                                                 void* __restrict__ Cp,
                                                 int M, int N, int K) {
  __shared__ __align__(16) u16 As[16 * 544];
  __shared__ __align__(16) u16 Bs[16 * 544];
  const int tid = threadIdx.x;
  const int wid = tid >> 6, lane = tid & 63;
  const int l32 = lane & 31, hi = lane >> 5;
  const int nbn = N >> 7;
  const int tm = blockIdx.x / nbn, tn = blockIdx.x % nbn;
  const int m0 = tm << 7, n0 = tn << 7;
  const int wr = wid >> 1, wc = wid & 1;

  f32x16 acc[2][2] = {};
  const int srow = (wid << 3) + (lane >> 3);  // row within 32-row staging chunk
  const int sblk = lane & 7;

  for (int kt = 0; kt < K; kt += 64) {
#pragma unroll
    for (int c = 0; c < 4; ++c) {
      int r = (c << 5) + srow;
      int gb = sblk ^ (r & 7);   // pre-swizzle source so LDS reads are conflict-lite
      gload_lds16(A  + (size_t)(m0 + r) * K + kt + (gb << 3), As + (c * 4 + wid) * 544);
      gload_lds16(BT + (size_t)(n0 + r) * K + kt + (gb << 3), Bs + (c * 4 + wid) * 544);
    }
    __syncthreads();
    bf16x8 af[2][4], bfr[2][4];
#pragma unroll
    for (int mi = 0; mi < 2; ++mi)
#pragma unroll
      for (int ks = 0; ks < 4; ++ks) {
        int ar = (wr << 6) + (mi << 5) + l32;
        int cb = (ks << 1) + hi;
        af[mi][ks] = *(const bf16x8*)(As + (ar >> 3) * 544 + ((ar & 7) << 6)
                                         + ((cb ^ (ar & 7)) << 3));
      }
#pragma unroll
    for (int ni = 0; ni < 2; ++ni)
#pragma unroll
      for (int ks = 0; ks < 4; ++ks) {
        int br = (wc << 6) + (ni << 5) + l32;
        int cb = (ks << 1) + hi;
        bfr[ni][ks] = *(const bf16x8*)(Bs + (br >> 3) * 544 + ((br & 7) << 6)
                                          + ((cb ^ (br & 7)) << 3));
      }
#pragma unroll
    for (int ks = 0; ks < 4; ++ks)
#pragma unroll
      for (int mi = 0; mi < 2; ++mi)
#pragma unroll
        for (int ni = 0; ni < 2; ++ni)
          acc[mi][ni] = __builtin_amdgcn_mfma_f32_32x32x16_bf16(af[mi][ks], bfr[ni][ks],
                                                                acc[mi][ni], 0, 0, 0);
    __syncthreads();
  }

#pragma unroll
  for (int mi = 0; mi < 2; ++mi)
#pragma unroll
    for (int ni = 0; ni < 2; ++ni) {
      int col = n0 + (wc << 6) + (ni << 5) + l32;
#pragma unroll
      for (int r = 0; r < 16; ++r) {
        int row = m0 + (wr << 6) + (mi << 5) + (r & 3) + ((r >> 2) << 3) + (hi << 2);
        if (OUTF32) ((float*)Cp)[(size_t)row * N + col] = acc[mi][ni][r];
        else        ((u16*)Cp)[(size_t)row * N + col]  = f2bf(acc[mi][ni][r]);
      }
    }
}

// ---------------- flash attention v7: 8-wave, 128 q-rows/block ----------------
// (unchanged from round 7 — verified)
__global__ __launch_bounds__(512) void k_attn(const u16* __restrict__ QKV,
                                              const u16* __restrict__ Kr,
                                              const u16* __restrict__ Vt,
                                              const float2* __restrict__ tab,
                                              const int* __restrict__ pos,
                                              u16* __restrict__ ctx) {
  __shared__ __align__(16) u16 Ks[2][64 * 128];
  __shared__ __align__(16) u16 Vs[2][128 * 64];
  __shared__ __align__(16) u16 Ps[8][16 * 72];
  const int bid = blockIdx.x;
  const int qt = 15 - (bid >> 6);          // longest-first
  const int bh = bid & 63;
  const int b = bh >> 5, h = bh & 31;
  const int kvh = h >> 2;
  const int tid = threadIdx.x;
  const int w = tid >> 6, lane = tid & 63;
  const int lrow = lane & 15, lk = lane >> 4;
  const int q0w = qt * 128 + w * 16;       // wave's first q row

  // ---- Q frags with RoPE fused (Q read once from qkvlin) ----
  const int s = q0w + lrow;
  const int p = pos[b * S_ + s];
  const u16* q0 = QKV + ((size_t)(b * S_ + s)) * NQKV_ + h * D_ + lk * 8;
  bf16x8 raw[4];
#pragma unroll
  for (int ks = 0; ks < 4; ++ks) raw[ks] = *(const bf16x8*)(q0 + ks * 32);
  bf16x8 qf[4];
#pragma unroll
  for (int ks = 0; ks < 2; ++ks)
#pragma unroll
    for (int e = 0; e < 8; ++e) {
      int d = ks * 32 + lk * 8 + e;
      float2 scv = tab[p * 64 + d];
      float x1 = bf2f((u16)raw[ks][e]), x2 = bf2f((u16)raw[ks + 2][e]);
      qf[ks][e]     = (short)f2bf(x1 * scv.y - x2 * scv.x);
      qf[ks + 2][e] = (short)f2bf(x2 * scv.y + x1 * scv.x);
    }

  float m[4] = {-1e30f, -1e30f, -1e30f, -1e30f};   // log2-domain running max
  float l[4] = {0.f, 0.f, 0.f, 0.f};
  f32x4 o[8] = {};

  const u16* kbase = Kr + (size_t)(b * KVH_ + kvh) * S_ * D_;
  const u16* vbase = Vt + (size_t)(b * KVH_ + kvh) * D_ * S_;
  const float cl = 0.12751743435f;  // (1/sqrt(128)) * log2(e)
  const int nt = 2 * qt + 2;

  auto STAGE = [&](int buf, int kb) {
    const int kv0 = kb << 6;
#pragma unroll
    for (int c = 0; c < 2; ++c) {          // K: 8 rows/wave, 4 rows/call
      int r = w * 8 + (lane >> 4) + c * 4;
      gload_lds16(kbase + (size_t)(kv0 + r) * D_ + (((lane & 15) ^ (r & 7)) << 3),
                  &Ks[buf][(w * 8 + c * 4) * 128]);
    }
#pragma unroll
    for (int c = 0; c < 2; ++c) {          // V^T: 16 rows/wave, 8 rows/call
      int r = w * 16 + (lane >> 3) + c * 8;
      gload_lds16(vbase + (size_t)r * S_ + kv0 + (((lane & 7) ^ (r & 7)) << 3),
                  &Vs[buf][(w * 16 + c * 8) * 64]);
    }
  };

  STAGE(0, 0);
  int cur = 0;
  for (int kb = 0; kb < nt; ++kb) {
    __syncthreads();                       // drains prev stage (vmcnt) + prev reads
    if (kb + 1 < nt) STAGE(cur ^ 1, kb + 1);
    const int kv0 = kb << 6;
    if (kv0 <= q0w + 15) {                 // wave-active tile
      const u16* Kb = &Ks[cur][0];
      const u16* Vb = &Vs[cur][0];

      // S = Q K^T (16 MFMAs)
      f32x4 sc[4] = {};
      __builtin_amdgcn_s_setprio(1);
#pragma unroll
      for (int n0 = 0; n0 < 4; ++n0) {
#pragma unroll
        for (int ks = 0; ks < 4; ++ks) {
          int krow = (n0 << 4) + lrow;
          bf16x8 kf = *(const bf16x8*)(Kb + krow * 128 + ((((ks << 2) + lk) ^ (krow & 7)) << 3));
          sc[n0] = __builtin_amdgcn_mfma_f32_16x16x32_bf16(qf[ks], kf, sc[n0], 0, 0, 0);
        }
      }
      __builtin_amdgcn_s_setprio(0);

      // scale (log2 domain) + causal mask (global indices) + online softmax
      const bool diag = (kv0 + 63 > q0w);
      float mnew[4] = {m[0], m[1], m[2], m[3]};
#pragma unroll
      for (int n0 = 0; n0 < 4; ++n0)
#pragma unroll
        for (int j = 0; j < 4; ++j) {
          float v = sc[n0][j] * cl;
          if (diag && (kv0 + (n0 << 4) + lrow > q0w + (lk << 2) + j)) v = -1e30f;
          sc[n0][j] = v;
          mnew[j] = fmaxf(mnew[j], v);
        }
#pragma unroll
      for (int j = 0; j < 4; ++j) {
        float v = mnew[j];
        v = fmaxf(v, __shfl_xor(v, 1));
        v = fmaxf(v, __shfl_xor(v, 2));
        v = fmaxf(v, __shfl_xor(v, 4));
        v = fmaxf(v, __shfl_xor(v, 8));
        mnew[j] = v;
      }
      float alpha[4], rs[4] = {0.f, 0.f, 0.f, 0.f};
#pragma unroll
      for (int j = 0; j < 4; ++j) { alpha[j] = exp2f(m[j] - mnew[j]); m[j] = mnew[j]; }
#pragma unroll
      for (int n0 = 0; n0 < 4; ++n0)
#pragma unroll
        for (int j = 0; j < 4; ++j) {
          float pv = exp2f(sc[n0][j] - m[j]);
          sc[n0][j] = pv;
          rs[j] += pv;
        }
#pragma unroll
      for (int j = 0; j < 4; ++j) {
        float v = rs[j];
        v += __shfl_xor(v, 1); v += __shfl_xor(v, 2);
        v += __shfl_xor(v, 4); v += __shfl_xor(v, 8);
        l[j] = l[j] * alpha[j] + v;
      }
#pragma unroll
      for (int db = 0; db < 8; ++db)
#pragma unroll
        for (int j = 0; j < 4; ++j)
          o[db][j] *= alpha[j];

      // P -> per-wave LDS (pitch 72 elems)
      u16* pw = &Ps[w][0];
#pragma unroll
      for (int n0 = 0; n0 < 4; ++n0)
#pragma unroll
        for (int j = 0; j < 4; ++j)
          pw[((lk << 2) + j) * 72 + (n0 << 4) + lrow] = f2bf(sc[n0][j]);

      // O += P V (16 MFMAs)
      __builtin_amdgcn_s_setprio(1);
#pragma unroll
      for (int t = 0; t < 2; ++t) {
        bf16x8 pf = *(const bf16x8*)(pw + lrow * 72 + (t << 5) + (lk << 3));
#pragma unroll
        for (int db = 0; db < 8; ++db) {
          int dr = (db << 4) + lrow;
          bf16x8 vf = *(const bf16x8*)(Vb + dr * 64 + ((((t << 2) + lk) ^ (dr & 7)) << 3));
          o[db] = __builtin_amdgcn_mfma_f32_16x16x32_bf16(pf, vf, o[db], 0, 0, 0);
        }
      }
      __builtin_amdgcn_s_setprio(0);
    }
    cur ^= 1;
  }

#pragma unroll
  for (int j = 0; j < 4; ++j) l[j] = 1.0f / l[j];
#pragma unroll
  for (int db = 0; db < 8; ++db)
#pragma unroll
    for (int j = 0; j < 4; ++j) {
      int q = q0w + (lk << 2) + j;
      ctx[((size_t)(b * S_ + q)) * HD_ + h * D_ + (db << 4) + lrow] = f2bf(o[db][j] * l[j]);
    }
}

extern "C" void kernel_launch(void* const* d_in, const int* in_sizes, int n_in,
                              void* d_out, int out_size, void* d_ws, size_t ws_size,
                              hipStream_t stream) {
  const float* hidden = (const float*)d_in[0];
  const float* Wq = (const float*)d_in[1];
  const float* Wk = (const float*)d_in[2];
  const float* Wv = (const float*)d_in[3];
  const float* Wo = (const float*)d_in[4];
  const int* pos_ids = (const int*)d_in[7];

  char* ws = (char*)d_ws;
  u16* hs      = (u16*)(ws);                    // [0,32M)   hidden bf16; later ctx
  u16* ctx     = hs;                            //           ctx [B,S,H*D]
  u16* wqkvt   = (u16*)(ws + 33554432ull);      // [32,80M)  stacked [6144][4096]; later WoT
  u16* wot     = wqkvt;
  u16* qkvlin  = (u16*)(ws + 83886080ull);      // [80,128M) qkv_lin [M][6144]
  u16* kr      = (u16*)(ws + 134217728ull);     // [128,136M) k rope'd [B,KVH,S,D]
  u16* vt      = (u16*)(ws + 142606336ull);     // [136,144M) v^T [B,KVH,D,S]
  float2* tab  = (float2*)(ws + 150994944ull);  // [144,145M) sin/cos table

  // 1. hidden -> bf16
  k_f2bf<<<dim3((M_*E_)/1024), dim3(256), 0, stream>>>(hidden, hs, M_*E_);
  // 2. stacked W^T: rows [0,4096)=Wq^T, [4096,5120)=Wk^T, [5120,6144)=Wv^T
  k_transpose_f2bf<<<dim3(HD_/32, E_/32), dim3(32, 8), 0, stream>>>(Wq, wqkvt, E_, HD_);
  k_transpose_f2bf<<<dim3(KVD_/32, E_/32), dim3(32, 8), 0, stream>>>(Wk, wqkvt + (size_t)HD_*E_, E_, KVD_);
  k_transpose_f2bf<<<dim3(KVD_/32, E_/32), dim3(32, 8), 0, stream>>>(Wv, wqkvt + (size_t)(HD_+KVD_)*E_, E_, KVD_);
  // 3. fused QKV projection: [M][6144]
  k_gemm_bt<false><<<dim3((M_/128)*(NQKV_/128)), dim3(256), 0, stream>>>(hs, wqkvt, (void*)qkvlin, M_, NQKV_, E_);
  // 4. Wo^T (reuses wqkvt region; QKV GEMM done)
  k_transpose_f2bf<<<dim3(E_/32, HD_/32), dim3(32, 8), 0, stream>>>(Wo, wot, HD_, E_);
  // 5. sin/cos table
  k_table<<<dim3((S_*64)/256), dim3(256), 0, stream>>>(tab);
  // 6. RoPE K -> kr [B,KVH,S,D] (Q rope is fused into k_attn)
  k_rope<<<dim3((B_*KVH_*S_*64)/256), dim3(256), 0, stream>>>(qkvlin + HD_, kr, tab, pos_ids, KVH_, NQKV_, B_*KVH_*S_*64);
  // 7. V transpose -> [B,KVH,D,S]
  k_transpose_v<<<dim3(S_/32, D_/32, B_*KVH_), dim3(32, 8), 0, stream>>>(qkvlin + HD_ + KVD_, vt, NQKV_);
  // 8. flash attention v7 -> ctx (hs region; hidden no longer needed)
  k_attn<<<dim3(B_*H_*(S_/128)), dim3(512), 0, stream>>>(qkvlin, kr, vt, tab, pos_ids, ctx);
  // 9. out = ctx @ Wo (fp32 epilogue)
  k_gemm_bt<true><<<dim3((M_/128)*(E_/128)), dim3(256), 0, stream>>>(ctx, wot, d_out, M_, E_, HD_);
}

// Round 9
// 687.287 us; speedup vs baseline: 1.0430x; 1.0430x over previous
//
#include <hip/hip_runtime.h>
#include <hip/hip_bf16.h>
#include <cstdint>
#include <cstddef>

#define B_ 2
#define S_ 2048
#define E_ 4096
#define H_ 32
#define KVH_ 8
#define D_ 128
#define M_ (B_*S_)      // 4096 rows (B*S)
#define HD_ (H_*D_)     // 4096
#define KVD_ (KVH_*D_)  // 1024
#define NQKV_ 6144      // HD_ + 2*KVD_

typedef unsigned short u16;
typedef __attribute__((ext_vector_type(8))) short bf16x8;
typedef __attribute__((ext_vector_type(4))) float f32x4;
typedef __attribute__((ext_vector_type(16))) float f32x16;

__device__ __forceinline__ float bf2f(u16 u) {
  union { float f; uint32_t i; } v; v.i = ((uint32_t)u) << 16; return v.f;
}
__device__ __forceinline__ u16 f2bf(float f) {
  union { float f; uint32_t i; } v; v.f = f;
  uint32_t r = v.i + 0x7FFF + ((v.i >> 16) & 1);   // RNE
  return (u16)(r >> 16);
}

// async global->LDS, 16B per lane; LDS dest = wave-uniform base + lane*16
__device__ __forceinline__ void gload_lds16(const void* g, void* l) {
  __builtin_amdgcn_global_load_lds(
      (const __attribute__((address_space(1))) void*)g,
      (__attribute__((address_space(3))) void*)l, 16, 0, 0);
}

// ---------------- elementwise f32 -> bf16 ----------------
__global__ __launch_bounds__(256) void k_f2bf(const float* __restrict__ in,
                                              u16* __restrict__ out, int n) {
  int i = (blockIdx.x * 256 + threadIdx.x) * 4;
  if (i + 3 < n) {
    float4 v = *(const float4*)(in + i);
    *(ushort4*)(out + i) = make_ushort4(f2bf(v.x), f2bf(v.y), f2bf(v.z), f2bf(v.w));
  }
}

// ---------------- transpose-convert f32 [R][C] -> bf16 [C][R] ----------------
__global__ __launch_bounds__(256) void k_transpose_f2bf(const float* __restrict__ in,
                                                        u16* __restrict__ out, int R, int C) {
  __shared__ float tile[32][33];
  int c0 = blockIdx.x * 32, r0 = blockIdx.y * 32;
  int lx = threadIdx.x, ly = threadIdx.y;
#pragma unroll
  for (int yy = 0; yy < 32; yy += 8)
    tile[ly + yy][lx] = in[(size_t)(r0 + ly + yy) * C + c0 + lx];
  __syncthreads();
#pragma unroll
  for (int yy = 0; yy < 32; yy += 8)
    out[(size_t)(c0 + ly + yy) * R + r0 + lx] = f2bf(tile[lx][ly + yy]);
}

// ---------- transpose v cols of qkvlin -> vt [B][KVH][D][S] (bf16) ----------
__global__ __launch_bounds__(256) void k_transpose_v(const u16* __restrict__ vlin,
                                                     u16* __restrict__ vt, int stride) {
  __shared__ u16 tile[32][33];
  int bk = blockIdx.z;             // b*KVH + kvh
  int b = bk >> 3, kvh = bk & 7;
  int s0 = blockIdx.x * 32, d0 = blockIdx.y * 32;
  int lx = threadIdx.x, ly = threadIdx.y;
#pragma unroll
  for (int yy = 0; yy < 32; yy += 8)
    tile[ly + yy][lx] = vlin[(size_t)(b * S_ + s0 + ly + yy) * stride + kvh * D_ + d0 + lx];
  __syncthreads();
#pragma unroll
  for (int yy = 0; yy < 32; yy += 8)
    vt[((size_t)bk * D_ + d0 + ly + yy) * S_ + s0 + lx] = tile[lx][ly + yy];
}

// ---------------- RoPE sin/cos table [S][64] ----------------
__global__ __launch_bounds__(256) void k_table(float2* __restrict__ tab) {
  int i = blockIdx.x * 256 + threadIdx.x;
  if (i < S_ * 64) {
    int s = i >> 6, d = i & 63;
    float inv = powf(10000.0f, -(float)d / 64.0f);
    float f = (float)s * inv;
    tab[i] = make_float2(sinf(f), cosf(f));
  }
}

// -------- RoPE + head reorder: strided cols of [B,S,*] -> [B,heads,S,D] --------
__global__ __launch_bounds__(256) void k_rope(const u16* __restrict__ in, u16* __restrict__ out,
                                              const float2* __restrict__ tab,
                                              const int* __restrict__ pos,
                                              int heads, int in_stride, int total) {
  int i = blockIdx.x * 256 + threadIdx.x;
  if (i >= total) return;
  int d = i & 63;
  int s = (i >> 6) & (S_ - 1);
  int bh = i >> 17;                 // 64*S_ = 2^17
  int h = bh % heads, b = bh / heads;
  size_t ibase = ((size_t)(b * S_ + s)) * in_stride + h * D_;
  float2 scv = tab[pos[b * S_ + s] * 64 + d];
  float x1 = bf2f(in[ibase + d]), x2 = bf2f(in[ibase + d + 64]);
  size_t obase = ((size_t)bh * S_ + s) * D_;
  out[obase + d]      = f2bf(x1 * scv.y - x2 * scv.x);
  out[obase + d + 64] = f2bf(x2 * scv.y + x1 * scv.x);
}

// ---------------- bf16 GEMM: C[M,N] = A[M,K] * BT[N,K]^T ----------------
// 128x128 tile, BK=64, 4 waves (2x2), 32x32x16 MFMA (r7-verified layout).
// + XCD-aware blockIdx swizzle (m157): contiguous original ids (same A-row
// panel) land on one XCD's L2. Requires gridDim %8 == 0 (1536/1024 here).
template<bool OUTF32>
__global__ __launch_bounds__(256) void k_gemm_bt(const u16* __restrict__ A,
                                                 const u16* __restrict__ BT,
                                                 void* __restrict__ Cp,
                                                 int M, int N, int K) {
  __shared__ __align__(16) u16 As[128 * 64];
  __shared__ __align__(16) u16 Bs[128 * 64];
  const int tid = threadIdx.x;
  const int wid = tid >> 6, lane = tid & 63;
  const int l32 = lane & 31, hi = lane >> 5;
  const int nbn = N >> 7;
  const int cpx = gridDim.x >> 3;
  const int bid = (blockIdx.x & 7) * cpx + (blockIdx.x >> 3);  // XCD swizzle
  const int tm = bid / nbn, tn = bid % nbn;
  const int m0 = tm << 7, n0 = tn << 7;
  const int wr = wid >> 1, wc = wid & 1;

  f32x16 acc[2][2] = {};
  const int srow = (wid << 3) + (lane >> 3);  // row within 32-row staging chunk
  const int sblk = lane & 7;

  for (int kt = 0; kt < K; kt += 64) {
#pragma unroll
    for (int c = 0; c < 4; ++c) {
      int r = (c << 5) + srow;
      int gb = sblk ^ (r & 7);   // pre-swizzle source so LDS reads are conflict-lite
      gload_lds16(A  + (size_t)(m0 + r) * K + kt + (gb << 3), As + (c << 11) + (wid << 9));
      gload_lds16(BT + (size_t)(n0 + r) * K + kt + (gb << 3), Bs + (c << 11) + (wid << 9));
    }
    __syncthreads();
    bf16x8 af[2][4], bfr[2][4];
#pragma unroll
    for (int mi = 0; mi < 2; ++mi)
#pragma unroll
      for (int ks = 0; ks < 4; ++ks) {
        int ar = (wr << 6) + (mi << 5) + l32;
        int cb = (ks << 1) + hi;
        af[mi][ks] = *(const bf16x8*)(As + ar * 64 + ((cb ^ (ar & 7)) << 3));
      }
#pragma unroll
    for (int ni = 0; ni < 2; ++ni)
#pragma unroll
      for (int ks = 0; ks < 4; ++ks) {
        int br = (wc << 6) + (ni << 5) + l32;
        int cb = (ks << 1) + hi;
        bfr[ni][ks] = *(const bf16x8*)(Bs + br * 64 + ((cb ^ (br & 7)) << 3));
      }
#pragma unroll
    for (int ks = 0; ks < 4; ++ks)
#pragma unroll
      for (int mi = 0; mi < 2; ++mi)
#pragma unroll
        for (int ni = 0; ni < 2; ++ni)
          acc[mi][ni] = __builtin_amdgcn_mfma_f32_32x32x16_bf16(af[mi][ks], bfr[ni][ks],
                                                                acc[mi][ni], 0, 0, 0);
    __syncthreads();
  }

#pragma unroll
  for (int mi = 0; mi < 2; ++mi)
#pragma unroll
    for (int ni = 0; ni < 2; ++ni) {
      int col = n0 + (wc << 6) + (ni << 5) + l32;
#pragma unroll
      for (int r = 0; r < 16; ++r) {
        int row = m0 + (wr << 6) + (mi << 5) + (r & 3) + ((r >> 2) << 3) + (hi << 2);
        if (OUTF32) ((float*)Cp)[(size_t)row * N + col] = acc[mi][ni][r];
        else        ((u16*)Cp)[(size_t)row * N + col]  = f2bf(acc[mi][ni][r]);
      }
    }
}

// ---------------- flash attention v8: 2 blocks/CU via Ps split ----------------
// v7 math unchanged. PV done in two kv-32 halves reusing a pitch-40 Ps buffer:
// LDS 82KB -> 74KB => 2 blocks/CU (4 waves/SIMD) for cross-wave overlap of the
// serial QK^T->softmax->PV chain. launch_bounds(512,4) caps VGPR at 128.
__global__ __launch_bounds__(512, 4) void k_attn(const u16* __restrict__ QKV,
                                                 const u16* __restrict__ Kr,
                                                 const u16* __restrict__ Vt,
                                                 const float2* __restrict__ tab,
                                                 const int* __restrict__ pos,
                                                 u16* __restrict__ ctx) {
  __shared__ __align__(16) u16 Ks[2][64 * 128];
  __shared__ __align__(16) u16 Vs[2][128 * 64];
  __shared__ __align__(16) u16 Ps[8][16 * 40];   // pitch 40 (80B): <=2-way banks
  const int bid = blockIdx.x;
  const int qt = 15 - (bid >> 6);          // longest-first
  const int bh = bid & 63;
  const int b = bh >> 5, h = bh & 31;
  const int kvh = h >> 2;
  const int tid = threadIdx.x;
  const int w = tid >> 6, lane = tid & 63;
  const int lrow = lane & 15, lk = lane >> 4;
  const int q0w = qt * 128 + w * 16;       // wave's first q row

  // ---- Q frags with RoPE fused (Q read once from qkvlin) ----
  const int s = q0w + lrow;
  const int p = pos[b * S_ + s];
  const u16* q0 = QKV + ((size_t)(b * S_ + s)) * NQKV_ + h * D_ + lk * 8;
  bf16x8 raw[4];
#pragma unroll
  for (int ks = 0; ks < 4; ++ks) raw[ks] = *(const bf16x8*)(q0 + ks * 32);
  bf16x8 qf[4];
#pragma unroll
  for (int ks = 0; ks < 2; ++ks)
#pragma unroll
    for (int e = 0; e < 8; ++e) {
      int d = ks * 32 + lk * 8 + e;
      float2 scv = tab[p * 64 + d];
      float x1 = bf2f((u16)raw[ks][e]), x2 = bf2f((u16)raw[ks + 2][e]);
      qf[ks][e]     = (short)f2bf(x1 * scv.y - x2 * scv.x);
      qf[ks + 2][e] = (short)f2bf(x2 * scv.y + x1 * scv.x);
    }

  float m[4] = {-1e30f, -1e30f, -1e30f, -1e30f};   // log2-domain running max
  float l[4] = {0.f, 0.f, 0.f, 0.f};
  f32x4 o[8] = {};

  const u16* kbase = Kr + (size_t)(b * KVH_ + kvh) * S_ * D_;
  const u16* vbase = Vt + (size_t)(b * KVH_ + kvh) * D_ * S_;
  const float cl = 0.12751743435f;  // (1/sqrt(128)) * log2(e)
  const int nt = 2 * qt + 2;

  auto STAGE = [&](int buf, int kb) {
    const int kv0 = kb << 6;
#pragma unroll
    for (int c = 0; c < 2; ++c) {          // K: 8 rows/wave, 4 rows/call
      int r = w * 8 + (lane >> 4) + c * 4;
      gload_lds16(kbase + (size_t)(kv0 + r) * D_ + (((lane & 15) ^ (r & 7)) << 3),
                  &Ks[buf][(w * 8 + c * 4) * 128]);
    }
#pragma unroll
    for (int c = 0; c < 2; ++c) {          // V^T: 16 rows/wave, 8 rows/call
      int r = w * 16 + (lane >> 3) + c * 8;
      gload_lds16(vbase + (size_t)r * S_ + kv0 + (((lane & 7) ^ (r & 7)) << 3),
                  &Vs[buf][(w * 16 + c * 8) * 64]);
    }
  };

  STAGE(0, 0);
  int cur = 0;
  for (int kb = 0; kb < nt; ++kb) {
    __syncthreads();                       // drains prev stage (vmcnt) + prev reads
    if (kb + 1 < nt) STAGE(cur ^ 1, kb + 1);
    const int kv0 = kb << 6;
    if (kv0 <= q0w + 15) {                 // wave-active tile
      const u16* Kb = &Ks[cur][0];
      const u16* Vb = &Vs[cur][0];

      // S = Q K^T (16 MFMAs)
      f32x4 sc[4] = {};
      __builtin_amdgcn_s_setprio(1);
#pragma unroll
      for (int n0 = 0; n0 < 4; ++n0) {
#pragma unroll
        for (int ks = 0; ks < 4; ++ks) {
          int krow = (n0 << 4) + lrow;
          bf16x8 kf = *(const bf16x8*)(Kb + krow * 128 + ((((ks << 2) + lk) ^ (krow & 7)) << 3));
          sc[n0] = __builtin_amdgcn_mfma_f32_16x16x32_bf16(qf[ks], kf, sc[n0], 0, 0, 0);
        }
      }
      __builtin_amdgcn_s_setprio(0);

      // scale (log2 domain) + causal mask (global indices) + online softmax
      const bool diag = (kv0 + 63 > q0w);
      float mnew[4] = {m[0], m[1], m[2], m[3]};
#pragma unroll
      for (int n0 = 0; n0 < 4; ++n0)
#pragma unroll
        for (int j = 0; j < 4; ++j) {
          float v = sc[n0][j] * cl;
          if (diag && (kv0 + (n0 << 4) + lrow > q0w + (lk << 2) + j)) v = -1e30f;
          sc[n0][j] = v;
          mnew[j] = fmaxf(mnew[j], v);
        }
#pragma unroll
      for (int j = 0; j < 4; ++j) {
        float v = mnew[j];
        v = fmaxf(v, __shfl_xor(v, 1));
        v = fmaxf(v, __shfl_xor(v, 2));
        v = fmaxf(v, __shfl_xor(v, 4));
        v = fmaxf(v, __shfl_xor(v, 8));
        mnew[j] = v;
      }
      float alpha[4], rs[4] = {0.f, 0.f, 0.f, 0.f};
#pragma unroll
      for (int j = 0; j < 4; ++j) { alpha[j] = exp2f(m[j] - mnew[j]); m[j] = mnew[j]; }
#pragma unroll
      for (int n0 = 0; n0 < 4; ++n0)
#pragma unroll
        for (int j = 0; j < 4; ++j) {
          float pv = exp2f(sc[n0][j] - m[j]);
          sc[n0][j] = pv;
          rs[j] += pv;
        }
#pragma unroll
      for (int j = 0; j < 4; ++j) {
        float v = rs[j];
        v += __shfl_xor(v, 1); v += __shfl_xor(v, 2);
        v += __shfl_xor(v, 4); v += __shfl_xor(v, 8);
        l[j] = l[j] * alpha[j] + v;
      }
#pragma unroll
      for (int db = 0; db < 8; ++db)
#pragma unroll
        for (int j = 0; j < 4; ++j)
          o[db][j] *= alpha[j];

      // ---- O += P V in two kv-32 halves (Ps pitch 40, reused) ----
      u16* pw = &Ps[w][0];
#pragma unroll
      for (int half = 0; half < 2; ++half) {
        // WAR fence: prior pass's reads (and writes) drained before overwrite
        asm volatile("s_waitcnt lgkmcnt(0)" ::: "memory");
#pragma unroll
        for (int n0 = 0; n0 < 2; ++n0)
#pragma unroll
          for (int j = 0; j < 4; ++j)
            pw[((lk << 2) + j) * 40 + (n0 << 4) + lrow] =
                f2bf(sc[(half << 1) + n0][j]);
        bf16x8 pf = *(const bf16x8*)(pw + lrow * 40 + (lk << 3));
        __builtin_amdgcn_s_setprio(1);
#pragma unroll
        for (int db = 0; db < 8; ++db) {
          int dr = (db << 4) + lrow;
          bf16x8 vf = *(const bf16x8*)(Vb + dr * 64 + ((((half << 2) + lk) ^ (dr & 7)) << 3));
          o[db] = __builtin_amdgcn_mfma_f32_16x16x32_bf16(pf, vf, o[db], 0, 0, 0);
        }
        __builtin_amdgcn_s_setprio(0);
      }
    }
    cur ^= 1;
  }

#pragma unroll
  for (int j = 0; j < 4; ++j) l[j] = 1.0f / l[j];
#pragma unroll
  for (int db = 0; db < 8; ++db)
#pragma unroll
    for (int j = 0; j < 4; ++j) {
      int q = q0w + (lk << 2) + j;
      ctx[((size_t)(b * S_ + q)) * HD_ + h * D_ + (db << 4) + lrow] = f2bf(o[db][j] * l[j]);
    }
}

extern "C" void kernel_launch(void* const* d_in, const int* in_sizes, int n_in,
                              void* d_out, int out_size, void* d_ws, size_t ws_size,
                              hipStream_t stream) {
  const float* hidden = (const float*)d_in[0];
  const float* Wq = (const float*)d_in[1];
  const float* Wk = (const float*)d_in[2];
  const float* Wv = (const float*)d_in[3];
  const float* Wo = (const float*)d_in[4];
  const int* pos_ids = (const int*)d_in[7];

  char* ws = (char*)d_ws;
  u16* hs      = (u16*)(ws);                    // [0,32M)   hidden bf16; later ctx
  u16* ctx     = hs;                            //           ctx [B,S,H*D]
  u16* wqkvt   = (u16*)(ws + 33554432ull);      // [32,80M)  stacked [6144][4096]; later WoT
  u16* wot     = wqkvt;
  u16* qkvlin  = (u16*)(ws + 83886080ull);      // [80,128M) qkv_lin [M][6144]
  u16* kr      = (u16*)(ws + 134217728ull);     // [128,136M) k rope'd [B,KVH,S,D]
  u16* vt      = (u16*)(ws + 142606336ull);     // [136,144M) v^T [B,KVH,D,S]
  float2* tab  = (float2*)(ws + 150994944ull);  // [144,145M) sin/cos table

  // 1. hidden -> bf16
  k_f2bf<<<dim3((M_*E_)/1024), dim3(256), 0, stream>>>(hidden, hs, M_*E_);
  // 2. stacked W^T: rows [0,4096)=Wq^T, [4096,5120)=Wk^T, [5120,6144)=Wv^T
  k_transpose_f2bf<<<dim3(HD_/32, E_/32), dim3(32, 8), 0, stream>>>(Wq, wqkvt, E_, HD_);
  k_transpose_f2bf<<<dim3(KVD_/32, E_/32), dim3(32, 8), 0, stream>>>(Wk, wqkvt + (size_t)HD_*E_, E_, KVD_);
  k_transpose_f2bf<<<dim3(KVD_/32, E_/32), dim3(32, 8), 0, stream>>>(Wv, wqkvt + (size_t)(HD_+KVD_)*E_, E_, KVD_);
  // 3. fused QKV projection: [M][6144]
  k_gemm_bt<false><<<dim3((M_/128)*(NQKV_/128)), dim3(256), 0, stream>>>(hs, wqkvt, (void*)qkvlin, M_, NQKV_, E_);
  // 4. Wo^T (reuses wqkvt region; QKV GEMM done)
  k_transpose_f2bf<<<dim3(E_/32, HD_/32), dim3(32, 8), 0, stream>>>(Wo, wot, HD_, E_);
  // 5. sin/cos table
  k_table<<<dim3((S_*64)/256), dim3(256), 0, stream>>>(tab);
  // 6. RoPE K -> kr [B,KVH,S,D] (Q rope is fused into k_attn)
  k_rope<<<dim3((B_*KVH_*S_*64)/256), dim3(256), 0, stream>>>(qkvlin + HD_, kr, tab, pos_ids, KVH_, NQKV_, B_*KVH_*S_*64);
  // 7. V transpose -> [B,KVH,D,S]
  k_transpose_v<<<dim3(S_/32, D_/32, B_*KVH_), dim3(32, 8), 0, stream>>>(qkvlin + HD_ + KVD_, vt, NQKV_);
  // 8. flash attention v8 -> ctx (hs region; hidden no longer needed)
  k_attn<<<dim3(B_*H_*(S_/128)), dim3(512), 0, stream>>>(qkvlin, kr, vt, tab, pos_ids, ctx);
  // 9. out = ctx @ Wo (fp32 epilogue)
  k_gemm_bt<true><<<dim3((M_/128)*(E_/128)), dim3(256), 0, stream>>>(ctx, wot, d_out, M_, E_, HD_);
}